// Round 1
// baseline (295.127 us; speedup 1.0000x reference)
//
#include <hip/hip_runtime.h>
#include <hip/hip_bf16.h>
#include <math.h>

#define B_ 32
#define T_ 2048
#define F_ 2048
#define H_ 1024
#define A_ 512

typedef __attribute__((ext_vector_type(8))) short short8;
typedef __attribute__((ext_vector_type(4))) float f32x4;

__device__ __forceinline__ unsigned short f2bf(float x) {
  union { float f; unsigned int u; } v; v.f = x;
  unsigned int r = v.u + 0x7FFFu + ((v.u >> 16) & 1u);
  return (unsigned short)(r >> 16);
}

// async global->LDS, 16B per lane; LDS dest = wave-uniform base + lane*16
#define GLOAD_LDS16(gp, lp) __builtin_amdgcn_global_load_lds( \
    (const __attribute__((address_space(1))) void*)(gp), \
    (__attribute__((address_space(3))) void*)(lp), 16, 0, 0)

// ---------------- kernel 1: W_a f32 -> bf16 ----------------
__global__ __launch_bounds__(256) void k_convert_wa(const float* __restrict__ wa,
                                                    unsigned short* __restrict__ out) {
  int i = (blockIdx.x * 256 + threadIdx.x) * 4;
  float4 v = *(const float4*)(wa + i);
  ushort4 o;
  o.x = f2bf(v.x); o.y = f2bf(v.y); o.z = f2bf(v.z); o.w = f2bf(v.w);
  *(ushort4*)(out + i) = o;
}

// ---------------- kernel 2: hcomb[b][a] = hidden[b]·W_h[a] + b_h[a] + b_a[a] ----------------
__global__ __launch_bounds__(256) void k_hproj(const float* __restrict__ hidden,
                                               const float* __restrict__ Wh,
                                               const float* __restrict__ bh,
                                               const float* __restrict__ ba,
                                               float* __restrict__ hcomb) {
  int gw = (blockIdx.x * 256 + threadIdx.x) >> 6;   // wave id 0..16383
  int lane = threadIdx.x & 63;
  int b = gw >> 9, a = gw & 511;
  const float* wr = Wh + a * H_;
  const float* hr = hidden + b * H_;
  float acc = 0.f;
  #pragma unroll
  for (int k = 0; k < H_; k += 256) {
    float4 w = *(const float4*)(wr + k + lane * 4);
    float4 h = *(const float4*)(hr + k + lane * 4);
    acc += w.x * h.x + w.y * h.y + w.z * h.z + w.w * h.w;
  }
  #pragma unroll
  for (int off = 32; off; off >>= 1) acc += __shfl_xor(acc, off);
  if (lane == 0) hcomb[gw] = acc + bh[a] + ba[a];
}

// ---------------- kernel 3: fused energy GEMM ----------------
// energy[m] = (sum_a tanh(hcomb[b][a] + feat[m]·W_a[a]) * v_w[a] + v_b) / sqrt(512)
// M = 65536 rows, K = 2048, N = 512 (full per block). BM=64, BK=64.
// 8 waves: wm = w>>2 (2 row-halves of 32), wn = w&3 (4 col slices of 128).
// LDS tiles XOR-swizzled: phys_byte(row,kb) = row*128 + (kb ^ ((row&7)<<4)).
__global__ __launch_bounds__(512, 4) void k_energy(
    const float* __restrict__ feat, const unsigned short* __restrict__ wab,
    const float* __restrict__ hcomb, const float* __restrict__ vw,
    const float* __restrict__ vb, float* __restrict__ energy) {
  __shared__ __align__(16) unsigned short Bs[512 * 64];  // 64 KB
  __shared__ __align__(16) unsigned short As[64 * 64];   // 8 KB
  __shared__ float s_h[512];
  __shared__ float s_v[512];
  __shared__ float e_red[64][4];

  const int tid = threadIdx.x;
  const int lane = tid & 63;
  const int w = tid >> 6;
  const int wm = w >> 2, wn = w & 3;
  const int m0 = blockIdx.x * 64;
  const int bb = m0 >> 11;

  s_h[tid] = hcomb[bb * 512 + tid];
  s_v[tid] = vw[tid];

  f32x4 acc[2][8] = {};

  // ---- A staging geometry: thread -> (row = tid>>3, 8 k-elems at (tid&7)*8)
  const int arow = tid >> 3;
  const unsigned short* const awp_base = As + arow * 64 +
      (((((tid & 7) * 16)) ^ ((arow & 7) << 4)) >> 1);
  const float* const aptr = feat + (size_t)(m0 + arow) * F_ + (tid & 7) * 8;

  // ---- B staging geometry (global_load_lds): round r writes LDS bytes
  // [r*8192 + tid*16); phys row n = r*64 + (tid>>3); logical k-bytes = rb ^ mask.
  const int bn = tid >> 3;
  const int blb = (((tid & 7) * 16) ^ ((bn & 7) << 4)) >> 1;  // k-elem offset
  const unsigned short* const bsrc = wab + bn * 2048 + blb;
  char* const ldsb = (char*)Bs + w * 1024;

  // ---- fragment read geometry
  const int lrow = lane & 15;
  const int xbase = ((lane >> 4) * 16) ^ ((lane & 7) << 4);  // swizzled k-byte, kk=0

  for (int ks = 0; ks < 32; ++ks) {
    const int k0 = ks * 64;
    __syncthreads();
    // B: 8 async rounds, 16 B/lane, linear LDS dest, pre-swizzled source
    const unsigned short* bs = bsrc + k0;
    #pragma unroll
    for (int r = 0; r < 8; ++r) {
      GLOAD_LDS16(bs + r * (64 * 2048), ldsb + r * 8192);
    }
    // A: load f32, convert RNE to bf16, swizzled ds_write_b128
    float4 av0 = *(const float4*)(aptr + k0);
    float4 av1 = *(const float4*)(aptr + k0 + 4);
    short8 apk;
    apk[0] = (short)f2bf(av0.x); apk[1] = (short)f2bf(av0.y);
    apk[2] = (short)f2bf(av0.z); apk[3] = (short)f2bf(av0.w);
    apk[4] = (short)f2bf(av1.x); apk[5] = (short)f2bf(av1.y);
    apk[6] = (short)f2bf(av1.z); apk[7] = (short)f2bf(av1.w);
    *(short8*)awp_base = apk;
    __syncthreads();
    // compute: 2 K-slices of 32
    #pragma unroll
    for (int kk = 0; kk < 2; ++kk) {
      const int xo = (xbase ^ (kk << 6)) >> 1;
      const unsigned short* Ab = As + (wm * 32 + lrow) * 64 + xo;
      short8 a0 = *(const short8*)(Ab);
      short8 a1 = *(const short8*)(Ab + 16 * 64);
      const unsigned short* Bb = Bs + (wn * 128 + lrow) * 64 + xo;
      #pragma unroll
      for (int ni = 0; ni < 8; ++ni) {
        short8 bf = *(const short8*)(Bb + ni * 16 * 64);
        acc[0][ni] = __builtin_amdgcn_mfma_f32_16x16x32_bf16(a0, bf, acc[0][ni], 0, 0, 0);
        acc[1][ni] = __builtin_amdgcn_mfma_f32_16x16x32_bf16(a1, bf, acc[1][ni], 0, 0, 0);
      }
    }
  }

  // ---- epilogue: tanh, dot with v, reduce over N
  const float vbv = vb[0];
  #pragma unroll
  for (int mi = 0; mi < 2; ++mi) {
    #pragma unroll
    for (int j = 0; j < 4; ++j) {
      float s = 0.f;
      #pragma unroll
      for (int ni = 0; ni < 8; ++ni) {
        int col = wn * 128 + ni * 16 + lrow;
        float x = acc[mi][ni][j] + s_h[col];
        s += tanhf(x) * s_v[col];
      }
      s += __shfl_xor(s, 1); s += __shfl_xor(s, 2);
      s += __shfl_xor(s, 4); s += __shfl_xor(s, 8);
      if (lrow == 0) e_red[wm * 32 + mi * 16 + (lane >> 4) * 4 + j][wn] = s;
    }
  }
  __syncthreads();
  if (tid < 64) {
    float s = e_red[tid][0] + e_red[tid][1] + e_red[tid][2] + e_red[tid][3];
    energy[m0 + tid] = (s + vbv) * 0.04419417382415922f;  // 1/sqrt(512)
  }
}

// ---------------- kernel 4: softmax over T per batch ----------------
__global__ __launch_bounds__(256) void k_softmax(const float* __restrict__ energy,
                                                 float* __restrict__ alpha) {
  const int b = blockIdx.x, tid = threadIdx.x;
  const float* e = energy + b * T_;
  float4 v0 = ((const float4*)e)[tid * 2];
  float4 v1 = ((const float4*)e)[tid * 2 + 1];
  float m = fmaxf(fmaxf(fmaxf(v0.x, v0.y), fmaxf(v0.z, v0.w)),
                  fmaxf(fmaxf(v1.x, v1.y), fmaxf(v1.z, v1.w)));
  #pragma unroll
  for (int off = 32; off; off >>= 1) m = fmaxf(m, __shfl_xor(m, off));
  __shared__ float rmax[4], rsum[4];
  const int lane = tid & 63, wv = tid >> 6;
  if (!lane) rmax[wv] = m;
  __syncthreads();
  m = fmaxf(fmaxf(rmax[0], rmax[1]), fmaxf(rmax[2], rmax[3]));
  float x0 = expf(v0.x - m), x1 = expf(v0.y - m), x2 = expf(v0.z - m), x3 = expf(v0.w - m);
  float x4 = expf(v1.x - m), x5 = expf(v1.y - m), x6 = expf(v1.z - m), x7 = expf(v1.w - m);
  float s = ((x0 + x1) + (x2 + x3)) + ((x4 + x5) + (x6 + x7));
  #pragma unroll
  for (int off = 32; off; off >>= 1) s += __shfl_xor(s, off);
  if (!lane) rsum[wv] = s;
  __syncthreads();
  s = (rsum[0] + rsum[1]) + (rsum[2] + rsum[3]);
  float inv = 1.f / s;
  float4 o0 = {x0 * inv, x1 * inv, x2 * inv, x3 * inv};
  float4 o1 = {x4 * inv, x5 * inv, x6 * inv, x7 * inv};
  float* ao = alpha + b * T_;
  ((float4*)ao)[tid * 2] = o0;
  ((float4*)ao)[tid * 2 + 1] = o1;
}

// ---------------- kernel 5: context partials over t-chunks ----------------
__global__ __launch_bounds__(256) void k_ctx_partial(const float* __restrict__ feat,
                                                     const float* __restrict__ alpha,
                                                     float* __restrict__ part) {
  const int b = blockIdx.x, fh = blockIdx.y, tc = blockIdx.z;
  const int tid = threadIdx.x;
  __shared__ float sa[256];
  sa[tid] = alpha[b * T_ + tc * 256 + tid];
  __syncthreads();
  const int f = fh * 1024 + tid * 4;
  const float* fp = feat + ((size_t)(b * T_ + tc * 256)) * F_ + f;
  float4 s = {0.f, 0.f, 0.f, 0.f};
  #pragma unroll 4
  for (int t = 0; t < 256; ++t) {
    float a = sa[t];
    float4 v = *(const float4*)(fp + (size_t)t * F_);
    s.x += a * v.x; s.y += a * v.y; s.z += a * v.z; s.w += a * v.w;
  }
  *(float4*)(part + ((size_t)(b * 8 + tc)) * F_ + f) = s;
}

// ---------------- kernel 6: reduce partials ----------------
__global__ __launch_bounds__(256) void k_ctx_reduce(const float* __restrict__ part,
                                                    float* __restrict__ ctx) {
  const int i4 = blockIdx.x * 256 + threadIdx.x;  // float4 index, 16384 total
  const int b = i4 >> 9, f4 = i4 & 511;
  const float4* p = (const float4*)part;
  float4 s = {0.f, 0.f, 0.f, 0.f};
  #pragma unroll
  for (int tc = 0; tc < 8; ++tc) {
    float4 v = p[((b * 8 + tc) << 9) + f4];
    s.x += v.x; s.y += v.y; s.z += v.z; s.w += v.w;
  }
  ((float4*)ctx)[i4] = s;
}

extern "C" void kernel_launch(void* const* d_in, const int* in_sizes, int n_in,
                              void* d_out, int out_size, void* d_ws, size_t ws_size,
                              hipStream_t stream) {
  const float* feat   = (const float*)d_in[0];
  const float* hidden = (const float*)d_in[1];
  const float* Wh     = (const float*)d_in[2];
  const float* bh     = (const float*)d_in[3];
  const float* Wa     = (const float*)d_in[4];
  const float* ba     = (const float*)d_in[5];
  const float* vw     = (const float*)d_in[6];
  const float* vb     = (const float*)d_in[7];

  float* ctx   = (float*)d_out;            // [32][2048]
  float* alpha = (float*)d_out + B_ * T_;  // [32][2048]

  char* ws = (char*)d_ws;
  unsigned short* wab = (unsigned short*)ws;               // 2 MB bf16 W_a
  float* hcomb  = (float*)(ws + 2097152);                  // 64 KB
  float* energy = (float*)(ws + 2097152 + 65536);          // 256 KB
  float* part   = (float*)(ws + 2097152 + 65536 + 262144); // 2 MB

  k_convert_wa<<<dim3(1024), dim3(256), 0, stream>>>(Wa, wab);
  k_hproj<<<dim3(4096), dim3(256), 0, stream>>>(hidden, Wh, bh, ba, hcomb);
  k_energy<<<dim3(1024), dim3(512), 0, stream>>>(feat, wab, hcomb, vw, vb, energy);
  k_softmax<<<dim3(32), dim3(256), 0, stream>>>(energy, alpha);
  k_ctx_partial<<<dim3(32, 2, 8), dim3(256), 0, stream>>>(feat, alpha, part);
  k_ctx_reduce<<<dim3(64), dim3(256), 0, stream>>>(part, ctx);
}